// Round 3
// baseline (272.172 us; speedup 1.0000x reference)
//
#include <hip/hip_runtime.h>
#include <hip/hip_bf16.h>
#include <cstdint>

#define N_NODES 100000
#define HIDDEN  128
#define NEDGE   524288   // E (pos edges; neg same count); 4096 blocks x 128
#define NTILES  1563     // ceil(N_NODES / 64)
#define PGRIDX  391      // blocks per table; each handles ~4 tiles

typedef __attribute__((ext_vector_type(8))) short short8;
typedef __attribute__((ext_vector_type(4))) float f32x4;

__device__ __forceinline__ unsigned short f2b(float f) {
    unsigned u = __float_as_uint(f);
    u += 0x7FFFu + ((u >> 16) & 1u);   // RNE; inputs are finite
    return (unsigned short)(u >> 16);
}
__device__ __forceinline__ float b2f(unsigned x16) {
    return __uint_as_float(x16 << 16);
}

// Wt[table][n][k] = bf16(W1[table*128 + k][n]) — one-time transpose to bf16.
__global__ void wt_kernel(const float* __restrict__ W1,
                          unsigned short* __restrict__ Wt)
{
    const int row = blockIdx.x;          // table*128 + n
    const int n = row & 127;
    const int tb = row >> 7;
    const int k = threadIdx.x;
    Wt[(size_t)row * 128 + k] = f2b(W1[(size_t)(tb * 128 + k) * 128 + n]);
}

// A[m][n] = sum_k z[m][k] * W1half[k][n], bf16 out.
// W fragments pre-swizzled into LDS once per block (immune to z-stream cache
// eviction — R2's Wt global loads were L1/L2-missing and serialized).
// Main loop is barrier-free; z is the only global load stream, 8 independent
// float4 loads per wave per tile, prefetched one tile ahead.
//   Aop[i=t][k=ks*32+q*8+j] = Wt[n*16+t][...]   (ds_read_b128, lane*16B)
//   Bop[k][j=t]             = bf16(z[m0+t][...])
//   D[i=q*4+r][j=t] -> A[m0+t][n*16 + q*4 + r]  (packed ushort4 store)
__global__ __launch_bounds__(256, 3)
void precompute_kernel(const float* __restrict__ z_src,
                       const float* __restrict__ z_dst,
                       const unsigned short* __restrict__ Wt,
                       unsigned short* __restrict__ Asrc,
                       unsigned short* __restrict__ Adst)
{
    const int table = blockIdx.y;
    const float* z = table ? z_dst : z_src;
    const unsigned short* W = Wt + table * (128 * 128);
    unsigned short* A = table ? Adst : Asrc;

    // fragbuf[nks][lane][8 bf16]: contiguous 16B per lane -> conflict-free b128
    __shared__ unsigned short fragbuf[32 * 64 * 8];  // 32 KB

    const int tid = threadIdx.x;
#pragma unroll
    for (int i = 0; i < 8; ++i) {
        const int f = tid + i * 256;          // f = (n*4+ks)*64 + q*16 + t
        const int nks = f >> 6;
        const int n = nks >> 2, ks = nks & 3;
        const int qq = (f >> 4) & 3, tt = f & 15;
        const short8 v = *(const short8*)(W + ((n * 16 + tt) * 128 + ks * 32 + qq * 8));
        *(short8*)&fragbuf[f * 8] = v;
    }
    __syncthreads();   // only barrier in the kernel

    const int wave = tid >> 6;
    const int lane = tid & 63;
    const int t = lane & 15;   // node-within-tile
    const int q = lane >> 4;   // K-chunk / D row-quad

    float4 s[8];
    int tile = blockIdx.x;
    {   // prologue load
        const int row = tile * 64 + wave * 16 + t;
        const bool ok = row < N_NODES;
        const float* zrow = z + (size_t)row * 128;
        const float4 zv = make_float4(0.f, 0.f, 0.f, 0.f);
#pragma unroll
        for (int ks = 0; ks < 4; ++ks) {
            s[2 * ks]     = ok ? *(const float4*)(zrow + ks * 32 + q * 8)     : zv;
            s[2 * ks + 1] = ok ? *(const float4*)(zrow + ks * 32 + q * 8 + 4) : zv;
        }
    }

    while (tile < NTILES) {
        const int row = tile * 64 + wave * 16 + t;
        const bool ok = row < N_NODES;

        // convert staged z -> bf16 B-fragments (frees s for the prefetch)
        short8 b[4];
#pragma unroll
        for (int ks = 0; ks < 4; ++ks) {
            const float4 v0 = s[2 * ks], v1 = s[2 * ks + 1];
            b[ks][0] = (short)f2b(v0.x); b[ks][1] = (short)f2b(v0.y);
            b[ks][2] = (short)f2b(v0.z); b[ks][3] = (short)f2b(v0.w);
            b[ks][4] = (short)f2b(v1.x); b[ks][5] = (short)f2b(v1.y);
            b[ks][6] = (short)f2b(v1.z); b[ks][7] = (short)f2b(v1.w);
        }

        // prefetch next tile while MFMAs run
        const int next = tile + PGRIDX;
        if (next < NTILES) {
            const int nrow = next * 64 + wave * 16 + t;
            const bool nok = nrow < N_NODES;
            const float* zrow = z + (size_t)nrow * 128;
            const float4 zv = make_float4(0.f, 0.f, 0.f, 0.f);
#pragma unroll
            for (int ks = 0; ks < 4; ++ks) {
                s[2 * ks]     = nok ? *(const float4*)(zrow + ks * 32 + q * 8)     : zv;
                s[2 * ks + 1] = nok ? *(const float4*)(zrow + ks * 32 + q * 8 + 4) : zv;
            }
        }

        f32x4 acc[8];
#pragma unroll
        for (int n = 0; n < 8; ++n) acc[n] = (f32x4){0.f, 0.f, 0.f, 0.f};

#pragma unroll
        for (int n = 0; n < 8; ++n) {
#pragma unroll
            for (int ks = 0; ks < 4; ++ks) {
                const short8 a = *(const short8*)&fragbuf[((n * 4 + ks) * 64 + lane) * 8];
                acc[n] = __builtin_amdgcn_mfma_f32_16x16x32_bf16(a, b[ks], acc[n], 0, 0, 0);
            }
        }

        unsigned short* arow = A + (size_t)row * 128;
#pragma unroll
        for (int n = 0; n < 8; ++n) {
            ushort4 h;
            h.x = f2b(acc[n][0]); h.y = f2b(acc[n][1]);
            h.z = f2b(acc[n][2]); h.w = f2b(acc[n][3]);
            if (ok) *(ushort4*)(arow + n * 16 + q * 4) = h;
        }
        tile = next;
    }
}

// 16 lanes per edge; lane owns 8 hidden units (16B bf16 gather per table).
// out[e] = sum_j relu(Asrc[s][j] + Adst[d][j] + b1[j]) * W2[j] + b2
__global__ __launch_bounds__(256, 4)
void edge_kernel(const unsigned short* __restrict__ Asrc,
                 const unsigned short* __restrict__ Adst,
                 const int* __restrict__ pos_src,
                 const int* __restrict__ pos_dst,
                 const int* __restrict__ neg_src,
                 const int* __restrict__ neg_dst,
                 const float* __restrict__ b1,
                 const float* __restrict__ W2,
                 const float* __restrict__ b2,
                 float* __restrict__ out)
{
    const int tid = threadIdx.x;
    const int t = tid & 15;      // hidden slice t*8 .. t*8+7
    const int g = tid >> 4;      // edge group within block (0..15)

    const bool is_pos = blockIdx.x < 4096;
    const int* __restrict__ sp = is_pos ? pos_src : neg_src;
    const int* __restrict__ dp = is_pos ? pos_dst : neg_dst;
    const int eb = (is_pos ? blockIdx.x : blockIdx.x - 4096) * 128;

    float b1r[8], w2r[8];
#pragma unroll
    for (int j = 0; j < 8; ++j) {
        b1r[j] = b1[t * 8 + j];
        w2r[j] = W2[t * 8 + j];
    }
    const float bias2 = b2[0];

    int sidx[8], didx[8];
#pragma unroll
    for (int i = 0; i < 8; ++i) {
        sidx[i] = sp[eb + i * 16 + g];
        didx[i] = dp[eb + i * 16 + g];
    }

    uint4 ua[8], ub[8];
#pragma unroll
    for (int i = 0; i < 8; ++i) {
        ua[i] = *(const uint4*)(Asrc + (size_t)sidx[i] * 128 + t * 8);
        ub[i] = *(const uint4*)(Adst + (size_t)didx[i] * 128 + t * 8);
    }

#pragma unroll
    for (int i = 0; i < 8; ++i) {
        float acc = 0.f;
        const unsigned* pa = (const unsigned*)&ua[i];
        const unsigned* pb = (const unsigned*)&ub[i];
#pragma unroll
        for (int j2 = 0; j2 < 4; ++j2) {
            float h0 = b2f(pa[j2] & 0xFFFFu) + b2f(pb[j2] & 0xFFFFu) + b1r[2 * j2];
            float h1 = b2f(pa[j2] >> 16)     + b2f(pb[j2] >> 16)     + b1r[2 * j2 + 1];
            h0 = fmaxf(h0, 0.f);
            h1 = fmaxf(h1, 0.f);
            acc = fmaf(h0, w2r[2 * j2], acc);
            acc = fmaf(h1, w2r[2 * j2 + 1], acc);
        }
        acc += __shfl_xor(acc, 1);
        acc += __shfl_xor(acc, 2);
        acc += __shfl_xor(acc, 4);
        acc += __shfl_xor(acc, 8);
        if (t == 0) out[blockIdx.x * 128 + i * 16 + g] = acc + bias2;
    }
}

extern "C" void kernel_launch(void* const* d_in, const int* in_sizes, int n_in,
                              void* d_out, int out_size, void* d_ws, size_t ws_size,
                              hipStream_t stream) {
    const float* z_src  = (const float*)d_in[0];
    const float* z_dst  = (const float*)d_in[1];
    const int* pos_src  = (const int*)d_in[2];
    const int* pos_dst  = (const int*)d_in[3];
    const int* neg_src  = (const int*)d_in[4];
    const int* neg_dst  = (const int*)d_in[5];
    const float* W1     = (const float*)d_in[6];
    const float* b1     = (const float*)d_in[7];
    const float* W2     = (const float*)d_in[8];
    const float* b2     = (const float*)d_in[9];
    float* out = (float*)d_out;

    unsigned short* Asrc = (unsigned short*)d_ws;                 // 25.6 MB
    unsigned short* Adst = Asrc + (size_t)N_NODES * HIDDEN;       // 25.6 MB
    unsigned short* Wt   = Adst + (size_t)N_NODES * HIDDEN;       // 64 KB

    wt_kernel<<<256, 128, 0, stream>>>(W1, Wt);

    dim3 pgrid(PGRIDX, 2);   // grid-stride over 1563 row-tiles, 2 tables
    precompute_kernel<<<pgrid, 256, 0, stream>>>(z_src, z_dst, Wt, Asrc, Adst);

    edge_kernel<<<8192, 256, 0, stream>>>(Asrc, Adst, pos_src, pos_dst,
                                          neg_src, neg_dst, b1, W2, b2, out);
}

// Round 4
// 222.372 us; speedup vs baseline: 1.2240x; 1.2240x over previous
//
#include <hip/hip_runtime.h>
#include <hip/hip_bf16.h>
#include <cstdint>

#define N_NODES 100000
#define HIDDEN  128
#define NEDGE   524288     // E; 2E = 8192 blocks x 128 edges
#define NT      6250       // 16-row wave-tiles per table (100000 = 16*6250 exact)
#define PBLK    256        // precompute grid.x
#define WSTRIDE (PBLK * 4) // wave-tile stride (4 waves/block)

typedef __attribute__((ext_vector_type(8))) short short8;
typedef __attribute__((ext_vector_type(4))) float f32x4;

__device__ __forceinline__ unsigned short f2b(float f) {
    unsigned u = __float_as_uint(f);
    u += 0x7FFFu + ((u >> 16) & 1u);   // RNE; inputs finite
    return (unsigned short)(u >> 16);
}
__device__ __forceinline__ float b2f(unsigned x16) {
    return __uint_as_float(x16 << 16);
}

// async 16B/lane global->LDS. lds dest must be wave-uniform; HW adds lane*16.
__device__ __forceinline__ void async_copy16(const float* g, float* l) {
    __builtin_amdgcn_global_load_lds(
        (const __attribute__((address_space(1))) unsigned int*)g,
        (__attribute__((address_space(3))) unsigned int*)l,
        16, 0, 0);
}

// Pack W1 halves into MFMA A-fragment order (bf16):
// Wp[tb][f=n*4+ks][lane][8] = W1[tb*128 + ks*32 + q*8 + j][n*16 + t], lane=q*16+t
__global__ void wp_kernel(const float* __restrict__ W1,
                          unsigned short* __restrict__ Wp)
{
    const int f = blockIdx.x;        // 0..31
    const int tb = blockIdx.y;       // 0..1
    const int lane = threadIdx.x;    // 0..63
    const int t = lane & 15, q = lane >> 4;
    const int n = f >> 2, ks = f & 3;
    short8 v;
#pragma unroll
    for (int j = 0; j < 8; ++j)
        v[j] = (short)f2b(W1[(size_t)(tb * 128 + ks * 32 + q * 8 + j) * 128 + n * 16 + t]);
    *(short8*)(Wp + ((size_t)(tb * 32 + f) * 64 + lane) * 8) = v;
}

// A[m][n] = sum_k z[m][k] * W1half[k][n], bf16 out.
// One wave per 16-row tile, grid-stride. W frags live in 128 VGPRs.
// z staged by global_load_lds (cannot be sunk by the compiler -> guaranteed
// 8KB/wave in flight), wave-private LDS double buffer, no __syncthreads.
// Source gather is XOR-swizzled (c ^= r&7) so frag ds_read_b128 is 2-way max.
__global__ __launch_bounds__(256, 2)
void precompute_kernel(const float* __restrict__ z_src,
                       const float* __restrict__ z_dst,
                       const unsigned short* __restrict__ Wp,
                       unsigned short* __restrict__ Asrc,
                       unsigned short* __restrict__ Adst)
{
    const int table = blockIdx.y;
    const float* __restrict__ z = table ? z_dst : z_src;
    unsigned short* __restrict__ A = table ? Adst : Asrc;

    __shared__ float zbuf[4][2][2048];   // 64 KB: per-wave double buffer

    const int tid = threadIdx.x;
    const int wave = tid >> 6;
    const int lane = tid & 63;
    const int t = lane & 15;
    const int q = lane >> 4;

    // W fragments -> registers (32 x short8 = 128 VGPR), coalesced 16B loads
    short8 wfrag[32];
    {
        const unsigned short* wp = Wp + ((size_t)table * 32 * 64 + lane) * 8;
#pragma unroll
        for (int f = 0; f < 32; ++f)
            wfrag[f] = *(const short8*)(wp + (size_t)f * 64 * 8);
    }

    // stage tile (rows m0..m0+15) into zbuf[wave][p]:
    // cell k=j*64+lane holds z[m0 + (k>>5)][4*((k&31)^((k>>5)&7)) .. +4]
    const int lhi = lane >> 5;       // 0/1
    const int llo = lane & 31;
#define STAGE(m0, p)                                                          \
    do {                                                                      \
        _Pragma("unroll")                                                     \
        for (int j = 0; j < 8; ++j) {                                         \
            const int r = j * 2 + lhi;                                        \
            const int c = llo ^ (r & 7);                                      \
            async_copy16(z + (size_t)((m0) + r) * 128 + c * 4,                \
                         &zbuf[wave][p][j * 256]);                            \
        }                                                                     \
    } while (0)

    int tile = blockIdx.x * 4 + wave;   // < 1024 < NT always
    int p = 0;
    STAGE(tile * 16, 0);
    __builtin_amdgcn_s_waitcnt(0xF70);  // vmcnt(0): tile0 + wfrags resident
    asm volatile("" ::: "memory");

    while (tile < NT) {
        const int m0 = tile * 16;
        const int ntile = tile + WSTRIDE;
        const int nm0 = (ntile < NT ? ntile : tile) * 16;  // clamp: dummy reload
        STAGE(nm0, p ^ 1);                  // issue next tile's 8 loads first
        asm volatile("" ::: "memory");
        __builtin_amdgcn_s_waitcnt(0xF78);  // vmcnt(8): all but the 8 above done
        asm volatile("" ::: "memory");

        // fragment reads + fp32->bf16 convert
        short8 b[4];
#pragma unroll
        for (int ks = 0; ks < 4; ++ks) {
            const int c0 = ks * 8 + 2 * q;
            const int s = t & 7;
            const float4 v0 = *(const float4*)&zbuf[wave][p][(t * 32 + (c0 ^ s)) * 4];
            const float4 v1 = *(const float4*)&zbuf[wave][p][(t * 32 + ((c0 + 1) ^ s)) * 4];
            b[ks][0] = (short)f2b(v0.x); b[ks][1] = (short)f2b(v0.y);
            b[ks][2] = (short)f2b(v0.z); b[ks][3] = (short)f2b(v0.w);
            b[ks][4] = (short)f2b(v1.x); b[ks][5] = (short)f2b(v1.y);
            b[ks][6] = (short)f2b(v1.z); b[ks][7] = (short)f2b(v1.w);
        }

        f32x4 acc[8];
#pragma unroll
        for (int n = 0; n < 8; ++n) acc[n] = (f32x4){0.f, 0.f, 0.f, 0.f};
#pragma unroll
        for (int n = 0; n < 8; ++n)
#pragma unroll
            for (int ks = 0; ks < 4; ++ks)
                acc[n] = __builtin_amdgcn_mfma_f32_16x16x32_bf16(
                             wfrag[n * 4 + ks], b[ks], acc[n], 0, 0, 0);

        // D: col=t, row=q*4+reg -> A[m0+t][n*16+q*4+reg]; packed 8B stores
        unsigned short* arow = A + (size_t)(m0 + t) * 128;
#pragma unroll
        for (int n = 0; n < 8; ++n) {
            ushort4 h;
            h.x = f2b(acc[n][0]); h.y = f2b(acc[n][1]);
            h.z = f2b(acc[n][2]); h.w = f2b(acc[n][3]);
            *(ushort4*)(arow + n * 16 + q * 4) = h;
        }

        p ^= 1;
        tile = ntile;
    }
#undef STAGE
}

// 16 lanes per edge; lane owns 8 hidden units (16B bf16 gather per table).
// out[e] = sum_j relu(Asrc[s][j] + Adst[d][j] + b1[j]) * W2[j] + b2
__global__ __launch_bounds__(256, 4)
void edge_kernel(const unsigned short* __restrict__ Asrc,
                 const unsigned short* __restrict__ Adst,
                 const int* __restrict__ pos_src,
                 const int* __restrict__ pos_dst,
                 const int* __restrict__ neg_src,
                 const int* __restrict__ neg_dst,
                 const float* __restrict__ b1,
                 const float* __restrict__ W2,
                 const float* __restrict__ b2,
                 float* __restrict__ out)
{
    const int tid = threadIdx.x;
    const int t = tid & 15;      // hidden slice t*8 .. t*8+7
    const int g = tid >> 4;      // edge group within block (0..15)

    const bool is_pos = blockIdx.x < 4096;
    const int* __restrict__ sp = is_pos ? pos_src : neg_src;
    const int* __restrict__ dp = is_pos ? pos_dst : neg_dst;
    const int eb = (is_pos ? blockIdx.x : blockIdx.x - 4096) * 128;

    float b1r[8], w2r[8];
#pragma unroll
    for (int j = 0; j < 8; ++j) {
        b1r[j] = b1[t * 8 + j];
        w2r[j] = W2[t * 8 + j];
    }
    const float bias2 = b2[0];

    int sidx[8], didx[8];
#pragma unroll
    for (int i = 0; i < 8; ++i) {
        sidx[i] = sp[eb + i * 16 + g];
        didx[i] = dp[eb + i * 16 + g];
    }

    uint4 ua[8], ub[8];
#pragma unroll
    for (int i = 0; i < 8; ++i) {
        ua[i] = *(const uint4*)(Asrc + (size_t)sidx[i] * 128 + t * 8);
        ub[i] = *(const uint4*)(Adst + (size_t)didx[i] * 128 + t * 8);
    }

#pragma unroll
    for (int i = 0; i < 8; ++i) {
        float acc = 0.f;
        const unsigned* pa = (const unsigned*)&ua[i];
        const unsigned* pb = (const unsigned*)&ub[i];
#pragma unroll
        for (int j2 = 0; j2 < 4; ++j2) {
            float h0 = b2f(pa[j2] & 0xFFFFu) + b2f(pb[j2] & 0xFFFFu) + b1r[2 * j2];
            float h1 = b2f(pa[j2] >> 16)     + b2f(pb[j2] >> 16)     + b1r[2 * j2 + 1];
            h0 = fmaxf(h0, 0.f);
            h1 = fmaxf(h1, 0.f);
            acc = fmaf(h0, w2r[2 * j2], acc);
            acc = fmaf(h1, w2r[2 * j2 + 1], acc);
        }
        acc += __shfl_xor(acc, 1);
        acc += __shfl_xor(acc, 2);
        acc += __shfl_xor(acc, 4);
        acc += __shfl_xor(acc, 8);
        if (t == 0) out[blockIdx.x * 128 + i * 16 + g] = acc + bias2;
    }
}

extern "C" void kernel_launch(void* const* d_in, const int* in_sizes, int n_in,
                              void* d_out, int out_size, void* d_ws, size_t ws_size,
                              hipStream_t stream) {
    const float* z_src  = (const float*)d_in[0];
    const float* z_dst  = (const float*)d_in[1];
    const int* pos_src  = (const int*)d_in[2];
    const int* pos_dst  = (const int*)d_in[3];
    const int* neg_src  = (const int*)d_in[4];
    const int* neg_dst  = (const int*)d_in[5];
    const float* W1     = (const float*)d_in[6];
    const float* b1     = (const float*)d_in[7];
    const float* W2     = (const float*)d_in[8];
    const float* b2     = (const float*)d_in[9];
    float* out = (float*)d_out;

    unsigned short* Asrc = (unsigned short*)d_ws;                 // 25.6 MB
    unsigned short* Adst = Asrc + (size_t)N_NODES * HIDDEN;       // 25.6 MB
    unsigned short* Wp   = Adst + (size_t)N_NODES * HIDDEN;       // 64 KB

    wp_kernel<<<dim3(32, 2), 64, 0, stream>>>(W1, Wp);

    precompute_kernel<<<dim3(PBLK, 2), 256, 0, stream>>>(z_src, z_dst, Wp,
                                                         Asrc, Adst);

    edge_kernel<<<8192, 256, 0, stream>>>(Asrc, Adst, pos_src, pos_dst,
                                          neg_src, neg_dst, b1, W2, b2, out);
}

// Round 5
// 222.309 us; speedup vs baseline: 1.2243x; 1.0003x over previous
//
#include <hip/hip_runtime.h>
#include <hip/hip_bf16.h>
#include <cstdint>

#define N_NODES 100000
#define HIDDEN  128
#define NEDGE   524288     // E; 2E = 8192 blocks x 128 edges
#define NT      6250       // 16-row wave-tiles per table (100000 = 16*6250)
#define PBLK    256        // precompute grid.x
#define WSTRIDE (PBLK * 4) // wave-tile stride (4 waves/block)

typedef __attribute__((ext_vector_type(8))) short short8;
typedef __attribute__((ext_vector_type(4))) float f32x4;

__device__ __forceinline__ unsigned short f2b(float f) {
    unsigned u = __float_as_uint(f);
    u += 0x7FFFu + ((u >> 16) & 1u);   // RNE; inputs finite
    return (unsigned short)(u >> 16);
}
__device__ __forceinline__ float b2f(unsigned x16) {
    return __uint_as_float(x16 << 16);
}

// async 16B/lane global->LDS. lds dest wave-uniform; HW adds lane*16.
__device__ __forceinline__ void async_copy16(const float* g, float* l) {
    __builtin_amdgcn_global_load_lds(
        (const __attribute__((address_space(1))) unsigned int*)g,
        (__attribute__((address_space(3))) unsigned int*)l,
        16, 0, 0);
}

// Pack W1 halves into MFMA A-fragment order (bf16):
// Wp[tb][f=n*4+ks][lane][8] = W1[tb*128 + ks*32 + q*8 + j][n*16 + t], lane=q*16+t
__global__ void wp_kernel(const float* __restrict__ W1,
                          unsigned short* __restrict__ Wp)
{
    const int f = blockIdx.x;        // 0..31
    const int tb = blockIdx.y;       // 0..1
    const int lane = threadIdx.x;    // 0..63
    const int t = lane & 15, q = lane >> 4;
    const int n = f >> 2, ks = f & 3;
    short8 v;
#pragma unroll
    for (int j = 0; j < 8; ++j)
        v[j] = (short)f2b(W1[(size_t)(tb * 128 + ks * 32 + q * 8 + j) * 128 + n * 16 + t]);
    *(short8*)(Wp + ((size_t)(tb * 32 + f) * 64 + lane) * 8) = v;
}

// A[m][n] = sum_k z[m][k] * W1half[k][n] (+ b1[n] for table 0), bf16 out.
// One wave per 16-row tile, grid-stride; W frags in 128 VGPRs; z staged by
// global_load_lds double-buffer (R4 structure). NEW: epilogue stages D
// through the consumed LDS buffer (XOR-swizzled) and stores 16B/lane full
// rows -> full-sector HBM writes (R3/R4's scattered 8B stores showed 2x
// WRITE_SIZE amplification).
__global__ __launch_bounds__(256, 2)
void precompute_kernel(const float* __restrict__ z_src,
                       const float* __restrict__ z_dst,
                       const unsigned short* __restrict__ Wp,
                       const float* __restrict__ b1,
                       unsigned short* __restrict__ Asrc,
                       unsigned short* __restrict__ Adst)
{
    const int table = blockIdx.y;
    const float* __restrict__ z = table ? z_dst : z_src;
    unsigned short* __restrict__ A = table ? Adst : Asrc;

    __shared__ float zbuf[4][2][2048];   // 64 KB: per-wave double buffer

    const int tid = threadIdx.x;
    const int wave = tid >> 6;
    const int lane = tid & 63;
    const int t = lane & 15;
    const int q = lane >> 4;

    // W fragments -> registers (32 x short8 = 128 VGPR)
    short8 wfrag[32];
    {
        const unsigned short* wp = Wp + ((size_t)table * 32 * 64 + lane) * 8;
#pragma unroll
        for (int f = 0; f < 32; ++f)
            wfrag[f] = *(const short8*)(wp + (size_t)f * 64 * 8);
    }

    // b1 folded into table 0 (out col = n*16 + q*4 + r)
    float4 b1v[8];
#pragma unroll
    for (int n = 0; n < 8; ++n)
        b1v[n] = (table == 0) ? *(const float4*)(b1 + n * 16 + q * 4)
                              : make_float4(0.f, 0.f, 0.f, 0.f);

    const int lhi = lane >> 5;       // 0/1
    const int llo = lane & 31;
#define STAGE(m0, p)                                                          \
    do {                                                                      \
        _Pragma("unroll")                                                     \
        for (int j = 0; j < 8; ++j) {                                         \
            const int r = j * 2 + lhi;                                        \
            const int c = llo ^ (r & 7);                                      \
            async_copy16(z + (size_t)((m0) + r) * 128 + c * 4,                \
                         &zbuf[wave][p][j * 256]);                            \
        }                                                                     \
    } while (0)

    int tile = blockIdx.x * 4 + wave;   // < 1024 < NT always
    int p = 0;
    STAGE(tile * 16, 0);
    __builtin_amdgcn_s_waitcnt(0xF70);  // vmcnt(0)
    asm volatile("" ::: "memory");

    while (tile < NT) {
        const int m0 = tile * 16;
        const int ntile = tile + WSTRIDE;
        const int nm0 = (ntile < NT ? ntile : tile) * 16;  // clamp: dummy reload
        STAGE(nm0, p ^ 1);                  // issue next tile's 8 loads first
        asm volatile("" ::: "memory");
        __builtin_amdgcn_s_waitcnt(0xF78);  // vmcnt(8)
        asm volatile("" ::: "memory");

        // fragment reads + fp32->bf16 convert
        short8 b[4];
#pragma unroll
        for (int ks = 0; ks < 4; ++ks) {
            const int c0 = ks * 8 + 2 * q;
            const int s = t & 7;
            const float4 v0 = *(const float4*)&zbuf[wave][p][(t * 32 + (c0 ^ s)) * 4];
            const float4 v1 = *(const float4*)&zbuf[wave][p][(t * 32 + ((c0 + 1) ^ s)) * 4];
            b[ks][0] = (short)f2b(v0.x); b[ks][1] = (short)f2b(v0.y);
            b[ks][2] = (short)f2b(v0.z); b[ks][3] = (short)f2b(v0.w);
            b[ks][4] = (short)f2b(v1.x); b[ks][5] = (short)f2b(v1.y);
            b[ks][6] = (short)f2b(v1.z); b[ks][7] = (short)f2b(v1.w);
        }

        f32x4 acc[8];
#pragma unroll
        for (int n = 0; n < 8; ++n) acc[n] = (f32x4){0.f, 0.f, 0.f, 0.f};
#pragma unroll
        for (int n = 0; n < 8; ++n)
#pragma unroll
            for (int ks = 0; ks < 4; ++ks)
                acc[n] = __builtin_amdgcn_mfma_f32_16x16x32_bf16(
                             wfrag[n * 4 + ks], b[ks], acc[n], 0, 0, 0);

        // ---- epilogue: stage D in LDS (buffer p is consumed), then
        // coalesced 16B/lane row stores. Row stride 136 ushort (272B, 16-mult);
        // 8B chunks XOR-swizzled by row -> read-back is 2-way (free).
        unsigned short* ob = (unsigned short*)&zbuf[wave][p][0];
        const int sw = (t & 7) * 2;
#pragma unroll
        for (int n = 0; n < 8; ++n) {
            ushort4 h;
            h.x = f2b(acc[n][0] + b1v[n].x);
            h.y = f2b(acc[n][1] + b1v[n].y);
            h.z = f2b(acc[n][2] + b1v[n].z);
            h.w = f2b(acc[n][3] + b1v[n].w);
            *(ushort4*)&ob[t * 136 + (((n * 4 + q) ^ sw) * 4)] = h;
        }
        const int rr = lane >> 4;            // 0..3
#pragma unroll
        for (int it = 0; it < 4; ++it) {
            const int r = it * 4 + rr;
            const uint4 v = *(const uint4*)&ob[r * 136 + (((2 * t) ^ ((r & 7) * 2)) * 4)];
            *(uint4*)(A + (size_t)(m0 + r) * 128 + t * 8) = v;
        }
        asm volatile("" ::: "memory");

        p ^= 1;
        tile = ntile;
    }
#undef STAGE
}

// 16 lanes per edge; lane owns 8 hidden units (16B bf16 gather per table).
// out[e] = sum_j relu(Asrc'[s][j] + Adst[d][j]) * W2[j] + b2   (b1 folded in)
// Software-pipelined: gather chunk c+1 (2 edges) issued before computing
// chunk c; asm memory clobbers stop the compiler sinking the gathers (R4's
// VGPR=48 proved it sank them). launch_bounds(256,6): ~24 waves/CU.
__global__ __launch_bounds__(256, 6)
void edge_kernel(const unsigned short* __restrict__ Asrc,
                 const unsigned short* __restrict__ Adst,
                 const int* __restrict__ pos_src,
                 const int* __restrict__ pos_dst,
                 const int* __restrict__ neg_src,
                 const int* __restrict__ neg_dst,
                 const float* __restrict__ W2,
                 const float* __restrict__ b2,
                 float* __restrict__ out)
{
    const int tid = threadIdx.x;
    const int t = tid & 15;      // hidden slice t*8 .. t*8+7
    const int g = tid >> 4;      // edge group within block (0..15)

    const bool is_pos = blockIdx.x < 4096;
    const int* __restrict__ sp = is_pos ? pos_src : neg_src;
    const int* __restrict__ dp = is_pos ? pos_dst : neg_dst;
    const int eb = (is_pos ? (int)blockIdx.x : (int)blockIdx.x - 4096) * 128;

    float w2r[8];
#pragma unroll
    for (int j = 0; j < 8; ++j) w2r[j] = W2[t * 8 + j];
    const float bias2 = b2[0];

    int sidx[8], didx[8];
#pragma unroll
    for (int i = 0; i < 8; ++i) {
        sidx[i] = sp[eb + i * 16 + g];
        didx[i] = dp[eb + i * 16 + g];
    }

    uint4 ua[2][2], ub[2][2];
#pragma unroll
    for (int k = 0; k < 2; ++k) {
        ua[0][k] = *(const uint4*)(Asrc + (size_t)sidx[k] * 128 + t * 8);
        ub[0][k] = *(const uint4*)(Adst + (size_t)didx[k] * 128 + t * 8);
    }
    asm volatile("" ::: "memory");

#pragma unroll
    for (int c = 0; c < 4; ++c) {
        if (c < 3) {
#pragma unroll
            for (int k = 0; k < 2; ++k) {
                ua[(c + 1) & 1][k] =
                    *(const uint4*)(Asrc + (size_t)sidx[(c + 1) * 2 + k] * 128 + t * 8);
                ub[(c + 1) & 1][k] =
                    *(const uint4*)(Adst + (size_t)didx[(c + 1) * 2 + k] * 128 + t * 8);
            }
        }
        asm volatile("" ::: "memory");
#pragma unroll
        for (int k = 0; k < 2; ++k) {
            const unsigned* pa = (const unsigned*)&ua[c & 1][k];
            const unsigned* pb = (const unsigned*)&ub[c & 1][k];
            float acc = 0.f;
#pragma unroll
            for (int j2 = 0; j2 < 4; ++j2) {
                float h0 = b2f(pa[j2] & 0xFFFFu) + b2f(pb[j2] & 0xFFFFu);
                float h1 = b2f(pa[j2] >> 16)     + b2f(pb[j2] >> 16);
                h0 = fmaxf(h0, 0.f);
                h1 = fmaxf(h1, 0.f);
                acc = fmaf(h0, w2r[2 * j2], acc);
                acc = fmaf(h1, w2r[2 * j2 + 1], acc);
            }
            acc += __shfl_xor(acc, 1);
            acc += __shfl_xor(acc, 2);
            acc += __shfl_xor(acc, 4);
            acc += __shfl_xor(acc, 8);
            if (t == 0) out[blockIdx.x * 128 + (c * 2 + k) * 16 + g] = acc + bias2;
        }
    }
}

extern "C" void kernel_launch(void* const* d_in, const int* in_sizes, int n_in,
                              void* d_out, int out_size, void* d_ws, size_t ws_size,
                              hipStream_t stream) {
    const float* z_src  = (const float*)d_in[0];
    const float* z_dst  = (const float*)d_in[1];
    const int* pos_src  = (const int*)d_in[2];
    const int* pos_dst  = (const int*)d_in[3];
    const int* neg_src  = (const int*)d_in[4];
    const int* neg_dst  = (const int*)d_in[5];
    const float* W1     = (const float*)d_in[6];
    const float* b1     = (const float*)d_in[7];
    const float* W2     = (const float*)d_in[8];
    const float* b2     = (const float*)d_in[9];
    float* out = (float*)d_out;

    unsigned short* Asrc = (unsigned short*)d_ws;                 // 25.6 MB
    unsigned short* Adst = Asrc + (size_t)N_NODES * HIDDEN;       // 25.6 MB
    unsigned short* Wp   = Adst + (size_t)N_NODES * HIDDEN;       // 64 KB

    wp_kernel<<<dim3(32, 2), 64, 0, stream>>>(W1, Wp);

    precompute_kernel<<<dim3(PBLK, 2), 256, 0, stream>>>(z_src, z_dst, Wp, b1,
                                                         Asrc, Adst);

    edge_kernel<<<8192, 256, 0, stream>>>(Asrc, Adst, pos_src, pos_dst,
                                          neg_src, neg_dst, W2, b2, out);
}